// Round 1
// baseline (1250.702 us; speedup 1.0000x reference)
//
#include <hip/hip_runtime.h>
#include <hip/hip_bf16.h>

#define B_   4
#define H_   128
#define W_   128
#define C_   256
#define NH_  8
#define D_   32
#define HID_ 1024
#define M_   65536   // B*H*W tokens per branch

typedef float  f4  __attribute__((ext_vector_type(4)));
typedef short  s8v __attribute__((ext_vector_type(8)));
typedef __hip_bfloat16 bf16;

// ---------------------------------------------------------------------------
// Weight convert + transpose: w1 [256,1024] -> w1t [1024,256] bf16
//                             w2 [1024,256] -> w2t [256,1024] bf16
// dst-major indexing: coalesced writes, strided reads absorbed by L2 (8MB src).
// ---------------------------------------------------------------------------
struct WP { const float* p[8]; };   // p[0..3]=w1 per branch, p[4..7]=w2 per branch

__global__ __launch_bounds__(256) void convert_w(WP wp,
                                                 bf16* __restrict__ w1t,
                                                 bf16* __restrict__ w2t)
{
    int d = blockIdx.x * 256 + threadIdx.x;     // 0 .. 2M-1 (8 * 262144)
    int which = d >> 18;
    int i = d & 262143;
    if (which < 4) {
        int n = i >> 8, k = i & 255;            // w1t[n][k] = w1[k][n]
        w1t[(size_t)which * 262144 + i] = __float2bfloat16(wp.p[which][k * HID_ + n]);
    } else {
        int br = which - 4;
        int n = i >> 10, k = i & 1023;          // w2t[n][k] = w2[k][n]
        w2t[(size_t)br * 262144 + i] = __float2bfloat16(wp.p[which][k * C_ + n]);
    }
}

// ---------------------------------------------------------------------------
// Window attention (ws=2): thread per (window, head, q-token).
// Computes out = softmax(QK^T/sqrt(32)) V in fp32, stores bf16 in image layout.
// ---------------------------------------------------------------------------
__global__ __launch_bounds__(256) void attn_kernel(const float* __restrict__ Q,
                                                   const float* __restrict__ KV,
                                                   bf16* __restrict__ outb)
{
    int tid = blockIdx.x * 256 + threadIdx.x;
    int t   = tid & 3;
    int h   = (tid >> 2) & 7;
    int win = tid >> 5;                      // 0..16383
    int ww = win & 63, wh = (win >> 6) & 63, b = win >> 12;
    int y = 2 * wh + (t >> 1), x = 2 * ww + (t & 1);
    int qrow = (b * H_ + y) * W_ + x;        // token linear index (image layout)

    const float4* qp = (const float4*)(Q + (size_t)qrow * C_ + h * D_);
    float4 q[8];
#pragma unroll
    for (int j = 0; j < 8; ++j) q[j] = qp[j];

    int kvbase = (b * H_ + 2 * wh) * W_ + 2 * ww;  // token (0,0) of window
    const int soff[4] = {0, C_, W_ * C_, W_ * C_ + C_};

    float dot[4];
#pragma unroll
    for (int s = 0; s < 4; ++s) {
        const float4* kp = (const float4*)(KV + (size_t)kvbase * C_ + soff[s] + h * D_);
        float acc = 0.f;
#pragma unroll
        for (int j = 0; j < 8; ++j) {
            float4 kk = kp[j];
            acc += q[j].x * kk.x + q[j].y * kk.y + q[j].z * kk.z + q[j].w * kk.w;
        }
        dot[s] = acc * 0.17677669529663687f;   // 1/sqrt(32)
    }
    float mx = fmaxf(fmaxf(dot[0], dot[1]), fmaxf(dot[2], dot[3]));
    float e[4]; float sum = 0.f;
#pragma unroll
    for (int s = 0; s < 4; ++s) { e[s] = expf(dot[s] - mx); sum += e[s]; }
    float inv = 1.f / sum;

    float4 o[8];
#pragma unroll
    for (int j = 0; j < 8; ++j) o[j] = float4{0.f, 0.f, 0.f, 0.f};
#pragma unroll
    for (int s = 0; s < 4; ++s) {
        float a = e[s] * inv;
        const float4* vp = (const float4*)(KV + (size_t)kvbase * C_ + soff[s] + h * D_);
#pragma unroll
        for (int j = 0; j < 8; ++j) {
            float4 vv = vp[j];
            o[j].x += a * vv.x; o[j].y += a * vv.y;
            o[j].z += a * vv.z; o[j].w += a * vv.w;
        }
    }

    bf16* op = outb + (size_t)qrow * C_ + h * D_;
#pragma unroll
    for (int j = 0; j < 8; ++j) {
        union { ushort4 u; bf16 b[4]; } pk;
        pk.b[0] = __float2bfloat16(o[j].x);
        pk.b[1] = __float2bfloat16(o[j].y);
        pk.b[2] = __float2bfloat16(o[j].z);
        pk.b[3] = __float2bfloat16(o[j].w);
        *(ushort4*)(op + j * 4) = pk.u;
    }
}

// ---------------------------------------------------------------------------
// bf16 MFMA GEMM, 128x128 tile, BK=32, 4 waves (2x2), 4x4 16x16x32 frags/wave.
// A [M,KDIM] row-major bf16; Bt [N,KDIM] row-major bf16 (pre-transposed weights).
// LDS chunk swizzle: physical 16B chunk = logical ^ ((row>>1)&3); applied on the
// pre-swizzled global source (global_load_lds writes linearly) and on ds_read.
// FC1: D = gelu(A@B + bias) -> bf16 Obf [M,NOUT]
// FC2: D = A@B + bias + resid(bf16) -> f32 Of [M,NOUT]
// ---------------------------------------------------------------------------
__device__ __forceinline__ float gelu_exact(float v) {
    return 0.5f * v * (1.0f + erff(v * 0.70710678118654752f));
}

template<int KDIM, bool FC1>
__global__ __launch_bounds__(256) void gemm_k(const bf16* __restrict__ A,
                                              const bf16* __restrict__ Bt,
                                              const float* __restrict__ bias,
                                              const bf16* __restrict__ resid,
                                              bf16* __restrict__ Obf,
                                              float* __restrict__ Of,
                                              int NOUT)
{
    __shared__ bf16 As[128 * 32];
    __shared__ bf16 Bs[128 * 32];

    const int tid  = threadIdx.x;
    const int wid  = tid >> 6;
    const int lane = tid & 63;
    const int m0 = blockIdx.x * 128;
    const int n0 = blockIdx.y * 128;

    // staging: per wave 2 calls for A, 2 for B; 1KB per call, linear LDS dest.
    const bf16* ga[2]; const bf16* gb[2]; int Lb[2];
#pragma unroll
    for (int c = 0; c < 2; ++c) {
        int L = (wid * 2 + c) * 1024 + lane * 16;    // byte offset in 8KB tile
        int row  = L >> 6;                           // 64B per row (32 bf16)
        int phys = (L >> 4) & 3;
        int logc = phys ^ ((row >> 1) & 3);          // inverse swizzle on source
        ga[c] = A  + (size_t)(m0 + row) * KDIM + logc * 8;
        gb[c] = Bt + (size_t)(n0 + row) * KDIM + logc * 8;
        Lb[c] = (wid * 2 + c) * 1024;                // wave-uniform LDS byte base
    }

    const int wm = (wid >> 1) * 64, wn = (wid & 1) * 64;
    const int llo = lane & 15, lhi = lane >> 4;
    int aoff[4], boff[4];
#pragma unroll
    for (int i = 0; i < 4; ++i) {
        int r = wm + i * 16 + llo;
        aoff[i] = r * 64 + ((lhi ^ ((r >> 1) & 3)) * 16);
    }
#pragma unroll
    for (int j = 0; j < 4; ++j) {
        int r = wn + j * 16 + llo;
        boff[j] = r * 64 + ((lhi ^ ((r >> 1) & 3)) * 16);
    }

    f4 acc[4][4] = {};

    for (int kt = 0; kt < KDIM / 32; ++kt) {
#pragma unroll
        for (int c = 0; c < 2; ++c) {
            __builtin_amdgcn_global_load_lds(
                (const __attribute__((address_space(1))) void*)(ga[c] + kt * 32),
                (__attribute__((address_space(3))) void*)((char*)As + Lb[c]), 16, 0, 0);
            __builtin_amdgcn_global_load_lds(
                (const __attribute__((address_space(1))) void*)(gb[c] + kt * 32),
                (__attribute__((address_space(3))) void*)((char*)Bs + Lb[c]), 16, 0, 0);
        }
        __syncthreads();   // compiler drains vmcnt before barrier

        s8v av[4], bv[4];
#pragma unroll
        for (int i = 0; i < 4; ++i) av[i] = *(const s8v*)((const char*)As + aoff[i]);
#pragma unroll
        for (int j = 0; j < 4; ++j) bv[j] = *(const s8v*)((const char*)Bs + boff[j]);
#pragma unroll
        for (int i = 0; i < 4; ++i)
#pragma unroll
            for (int j = 0; j < 4; ++j)
                acc[i][j] = __builtin_amdgcn_mfma_f32_16x16x32_bf16(av[i], bv[j], acc[i][j], 0, 0, 0);
        __syncthreads();
    }

    // epilogue: D row = (lane>>4)*4 + reg, col = lane&15 (verified layout)
#pragma unroll
    for (int i = 0; i < 4; ++i) {
        int row0 = m0 + wm + i * 16 + lhi * 4;
#pragma unroll
        for (int j = 0; j < 4; ++j) {
            int col = n0 + wn + j * 16 + llo;
            float bsv = bias[col];
#pragma unroll
            for (int r = 0; r < 4; ++r) {
                int row = row0 + r;
                float v = acc[i][j][r] + bsv;
                if (FC1) {
                    v = gelu_exact(v);
                    Obf[(size_t)row * NOUT + col] = __float2bfloat16(v);
                } else {
                    v += __bfloat162float(resid[(size_t)row * C_ + col]);
                    Of[(size_t)row * NOUT + col] = v;
                }
            }
        }
    }
}

// ---------------------------------------------------------------------------
extern "C" void kernel_launch(void* const* d_in, const int* in_sizes, int n_in,
                              void* d_out, int out_size, void* d_ws, size_t ws_size,
                              hipStream_t stream)
{
    const float* img[4] = {(const float*)d_in[0], (const float*)d_in[1],
                           (const float*)d_in[2], (const float*)d_in[3]};
    static const int kvidx[4] = {1, 2, 3, 1};   // r<-g, g<-b, b<-ir, ir<-g

    char* ws = (char*)d_ws;
    bf16* w1t = (bf16*)ws;                            // 4*262144*2B = 2 MB
    bf16* w2t = (bf16*)(ws + 2097152);                // 2 MB
    bf16* outb = (bf16*)(ws + 4194304);               // 65536*256*2B = 32 MB
    bf16* hmid = (bf16*)(ws + 4194304 + 33554432);    // chunk*1024*2B
    size_t fixed = 4194304 + 33554432;

    int chunk = M_;
    while (chunk > 128 && fixed + (size_t)chunk * HID_ * 2 > ws_size) chunk >>= 1;

    WP wp;
    for (int br = 0; br < 4; ++br) {
        wp.p[br]     = (const float*)d_in[4 + 4 * br];   // w1
        wp.p[4 + br] = (const float*)d_in[6 + 4 * br];   // w2
    }
    convert_w<<<8192, 256, 0, stream>>>(wp, w1t, w2t);

    for (int br = 0; br < 4; ++br) {
        attn_kernel<<<2048, 256, 0, stream>>>(img[br], img[kvidx[br]], outb);
        const float* b1 = (const float*)d_in[5 + 4 * br];
        const float* b2 = (const float*)d_in[7 + 4 * br];
        float* outp = (float*)d_out + (size_t)br * M_ * C_;
        for (int ms = 0; ms < M_; ms += chunk) {
            gemm_k<256, true><<<dim3(chunk / 128, 8), 256, 0, stream>>>(
                outb + (size_t)ms * C_, w1t + (size_t)br * 262144, b1,
                nullptr, hmid, nullptr, HID_);
            gemm_k<1024, false><<<dim3(chunk / 128, 2), 256, 0, stream>>>(
                hmid, w2t + (size_t)br * 262144, b2,
                outb + (size_t)ms * C_, nullptr, outp + (size_t)ms * C_, C_);
        }
    }
}